// Round 5
// baseline (758.948 us; speedup 1.0000x reference)
//
#include <hip/hip_runtime.h>
#include <hip/hip_bf16.h>
#include <hip/hip_fp16.h>

// Problem constants
#define NB 8
#define NT 1024
#define MD 1024
#define SD 256
#define NSTATES 16
#define NTOK (NB*NT)            // 8192
#define OUT_MAIN (NTOK*MD)      // 8388608

typedef __attribute__((ext_vector_type(8))) short bf16x8;
typedef __attribute__((ext_vector_type(4))) float f32x4;

static __device__ __forceinline__ unsigned short f32_to_bf16_bits(float f) {
    union { float f; unsigned u; } v; v.f = f;
    unsigned r = v.u + 0x7FFFu + ((v.u >> 16) & 1u);
    return (unsigned short)(r >> 16);
}

#if defined(__has_builtin)
#if __has_builtin(__builtin_amdgcn_sdot4)
#define DOT4(acc, h, w) acc = __builtin_amdgcn_sdot4((int)(h), (int)(w), acc, false)
#endif
#endif
#ifndef DOT4
#define DOT4(acc, h, w) asm("v_dot4_i32_i8 %0, %1, %2, %0" : "+v"(acc) : "v"(h), "v"(w))
#endif

static __device__ __forceinline__ float fast_exp2(float x) {
#if __has_builtin(__builtin_amdgcn_exp2f)
    return __builtin_amdgcn_exp2f(x);
#else
    return exp2f(x);
#endif
}
static __device__ __forceinline__ float fast_rcp(float x) {
#if __has_builtin(__builtin_amdgcn_rcpf)
    return __builtin_amdgcn_rcpf(x);
#else
    return 1.f / x;
#endif
}

// int butterfly-add over 8 consecutive lanes: xor1, xor2, mirror-within-8
static __device__ __forceinline__ int bsum8(int v) {
    v += __builtin_amdgcn_update_dpp(0, v, 0xB1,  0xF, 0xF, true);  // quad_perm [1,0,3,2]
    v += __builtin_amdgcn_update_dpp(0, v, 0x4E,  0xF, 0xF, true);  // quad_perm [2,3,0,1]
    v += __builtin_amdgcn_update_dpp(0, v, 0x141, 0xF, 0xF, true);  // row_half_mirror
    return v;
}

// async global(16B/lane) -> LDS (wave-uniform base, lane*16 stride)
static __device__ __forceinline__ void gld16(const void* g, void* l) {
    __builtin_amdgcn_global_load_lds(
        (const __attribute__((address_space(1))) void*)g,
        (__attribute__((address_space(3))) void*)l, 16, 0, 0);
}

#define STEP_BARRIER() do { \
    asm volatile("s_waitcnt lgkmcnt(0)" ::: "memory"); \
    __builtin_amdgcn_s_barrier(); \
    asm volatile("" ::: "memory"); } while (0)

// ---------------------------------------------------------------------------
// K1: out = base (exact f32 copy), zero accumulators (ent_sum f32, count u32)
__global__ void k_copy_zero(const float4* __restrict__ base, float4* __restrict__ out,
                            float* __restrict__ accums) {
    unsigned i = blockIdx.x * 256u + threadIdx.x;
    const unsigned STRIDE = 524288u; // total float4 = 2097152
#pragma unroll
    for (int q = 0; q < 4; q++) out[i + q * STRIDE] = base[i + q * STRIDE];
    if (i == 0u) { accums[0] = 0.f; ((unsigned*)accums)[1] = 0u; }
}

// ---------------------------------------------------------------------------
// K2: prep weights + active list.
//  - Bt[512][1024] bf16 : row n = column n of [Wsi|Wgi]
//  - Wpack: int8 recurrent weights (scale 1270) for the 1024-thread k_rec:
//    uint w = 4*(i4*1024+tid)+e is WRONG reading order; layout is
//    Wpack[(i4*1024+tid)*? ] -- precisely: linear index w in [0,32768):
//      e=w&3, tid=(w>>2)&1023, i4=w>>12 (0..7): q=i4&1, a=i4>>1 (0..3)
//      lane=tid&63, wv=tid>>6, ko=lane&7, jg=lane>>3, G=wv*8+jg,
//      j=2G+(a&1), o=a>>1 (0:Wsh,1:Wgh), c=(q^(ko&1))&1, k0=ko*32+c*16+e*4
//      uint packs W_o[k0+r][j], r=0..3 (little-endian bytes)
//    k_rec reads uint4 w[a][q] = Wpack4[(a*2+q)*1024 + tid]
//  - active list: (tok<<6)|slot appended with atomic counter
__global__ void k_prep(const float* __restrict__ Wsi, const float* __restrict__ Wgi,
                       const float* __restrict__ Wsh, const float* __restrict__ Wgh,
                       const int* __restrict__ ids, const int* __restrict__ t2s,
                       unsigned short* __restrict__ Bt, unsigned* __restrict__ Wpack,
                       unsigned* __restrict__ list, unsigned* __restrict__ countp) {
    unsigned i = blockIdx.x * 256u + threadIdx.x;
    if (i < 524288u) {
        unsigned n = i >> 10, k = i & 1023u;
        float v = (n < 256u) ? Wsi[k * 256u + n] : Wgi[k * 256u + (n - 256u)];
        Bt[i] = f32_to_bf16_bits(v);
    } else if (i < 557056u) {
        unsigned w = i - 524288u;            // 0..32767
        unsigned e   = w & 3u;
        unsigned tid = (w >> 2) & 1023u;
        unsigned i4  = w >> 12;              // 0..7
        unsigned q   = i4 & 1u;
        unsigned a   = i4 >> 1;              // 0..3
        unsigned lane = tid & 63u, wv = tid >> 6;
        unsigned ko = lane & 7u, jg = lane >> 3;
        unsigned G  = wv * 8u + jg;
        unsigned j  = 2u * G + (a & 1u);
        unsigned c  = (q ^ (ko & 1u)) & 1u;
        unsigned k0 = ko * 32u + c * 16u + e * 4u;
        const float* W = (a >> 1) ? Wgh : Wsh;
        unsigned word = 0u;
#pragma unroll
        for (int r = 0; r < 4; r++) {
            float wf = W[(k0 + (unsigned)r) * 256u + j];
            int iv = (int)rintf(wf * 1270.f);
            iv = iv > 127 ? 127 : (iv < -127 ? -127 : iv);
            word |= ((unsigned)iv & 0xFFu) << (8 * r);
        }
        Wpack[w] = word;
    } else if (i < 565248u) {
        unsigned tok = i - 557056u;
        int slot = t2s[ids[tok]];
        if (slot >= 0) {
            unsigned pos = atomicAdd(countp, 1u);
            list[pos] = (tok << 6) | (unsigned)slot;
        }
    }
}

// ---------------------------------------------------------------------------
// K3: XW[8192][512] f32 = bf16(base) @ [Wsi|Wgi]  (unchanged)
__launch_bounds__(512, 1)
__global__ void k_gemm(const float* __restrict__ A, const unsigned short* __restrict__ Bt,
                       float* __restrict__ XW) {
    __shared__ __align__(16) unsigned short Abuf[128 * 40];
    __shared__ __align__(16) unsigned short Bbuf[256 * 40];
    const unsigned tid = threadIdx.x;
    const unsigned m0 = blockIdx.x * 128u;
    const unsigned n0 = blockIdx.y * 256u;
    const unsigned wave = tid >> 6, lane = tid & 63u;
    const unsigned wm = wave >> 2, wn = wave & 3u;
    const unsigned l15 = lane & 15u, kg = lane >> 4;
    const unsigned ar = tid >> 2;
    const unsigned ac = (tid & 3u) * 8u;

    f32x4 acc[4][4];
#pragma unroll
    for (int i = 0; i < 4; i++)
#pragma unroll
        for (int j = 0; j < 4; j++) acc[i][j] = (f32x4){0.f, 0.f, 0.f, 0.f};

    for (unsigned k0 = 0; k0 < 1024u; k0 += 32u) {
        {
            const float* src = A + (size_t)(m0 + ar) * 1024u + k0 + ac;
            float4 f0 = *(const float4*)src;
            float4 f1 = *(const float4*)(src + 4);
            unsigned short* dst = &Abuf[ar * 40u + ac];
            dst[0] = f32_to_bf16_bits(f0.x); dst[1] = f32_to_bf16_bits(f0.y);
            dst[2] = f32_to_bf16_bits(f0.z); dst[3] = f32_to_bf16_bits(f0.w);
            dst[4] = f32_to_bf16_bits(f1.x); dst[5] = f32_to_bf16_bits(f1.y);
            dst[6] = f32_to_bf16_bits(f1.z); dst[7] = f32_to_bf16_bits(f1.w);
        }
#pragma unroll
        for (int q = 0; q < 2; q++) {
            unsigned br = q * 128u + (tid >> 2);
            const unsigned short* src = Bt + (size_t)(n0 + br) * 1024u + k0 + ac;
            *(uint4*)&Bbuf[br * 40u + ac] = *(const uint4*)src;
        }
        __syncthreads();
        bf16x8 a[4], b[4];
#pragma unroll
        for (int i = 0; i < 4; i++)
            a[i] = *(const bf16x8*)&Abuf[(wm * 64u + i * 16u + l15) * 40u + kg * 8u];
#pragma unroll
        for (int j = 0; j < 4; j++)
            b[j] = *(const bf16x8*)&Bbuf[(wn * 64u + j * 16u + l15) * 40u + kg * 8u];
#pragma unroll
        for (int i = 0; i < 4; i++)
#pragma unroll
            for (int j = 0; j < 4; j++)
                acc[i][j] = __builtin_amdgcn_mfma_f32_16x16x32_bf16(a[i], b[j], acc[i][j], 0, 0, 0);
        __syncthreads();
    }
#pragma unroll
    for (int i = 0; i < 4; i++) {
        unsigned row_b = m0 + wm * 64u + i * 16u + kg * 4u;
#pragma unroll
        for (int j = 0; j < 4; j++) {
            unsigned col = n0 + wn * 64u + j * 16u + l15;
#pragma unroll
            for (int r = 0; r < 4; r++)
                XW[(size_t)(row_b + r) * 512u + col] = acc[i][j][r];
        }
    }
}

// ---------------------------------------------------------------------------
// K4: sequential GRU recurrence, v5 (int8 dot4, 1024 threads).
// One WG per batch, 1024 threads (16 waves, 4/SIMD). Lane octet (ko=lane&7)
// splits K into eighths; octet (wv, jg) owns columns j0=2G, j1=2G+1 (G=wv*8+jg)
// for both s and g -> 4 accs/thread, 32 dot4/thread/step (32 weight VGPRs).
// DPP butterfly reduce; h i8 double-buffered in LDS; one barrier/step; xw
// staged in 8-step chunks via global_load_lds with counted vmcnt(8).
__launch_bounds__(1024, 4)
__global__ void k_rec(const float* __restrict__ XW, const unsigned* __restrict__ Wpack,
                      float* __restrict__ prefix) {
    __shared__ __align__(16) unsigned char hB[2][256];
    __shared__ __align__(16) float xwC[2][8 * 512];
    const unsigned tid = threadIdx.x;
    const unsigned lane = tid & 63u, wv = tid >> 6;
    const unsigned ko = lane & 7u, jg = lane >> 3;
    const unsigned G = wv * 8u + jg;
    const unsigned jc = ko & 1u;
    const unsigned j = 2u * G + jc;
    const unsigned b = blockIdx.x;

    // register-resident weights: 8 uint4 = 32 VGPRs of packed i8
    uint4 w[4][2];
#pragma unroll
    for (int a = 0; a < 4; a++)
#pragma unroll
        for (int q = 0; q < 2; q++)
            w[a][q] = ((const uint4*)Wpack)[(a * 2 + q) * 1024 + tid];

    if (tid < 128u) ((unsigned*)&hB[0][0])[tid] = 0u;   // zero both h buffers

    // per-lane h read offsets (XOR order across the octet -> benign 2-way)
    const unsigned c0 = ko & 1u;
    const unsigned off_q0 = ko * 32u + c0 * 16u;
    const unsigned off_q1 = ko * 32u + (c0 ^ 1u) * 16u;
    const unsigned char* hbp0 = &hB[0][0];
    const unsigned char* hbp1 = &hB[1][0];

    const float* xwb = XW + (size_t)b * (1024u * 512u);
    float* pfb = prefix + (size_t)b * (1024u * 256u) + j;

    // chunk c = 8 steps = 4096 floats; each wave issues ONE gld16 (1 KB slice)
    auto issue = [&](unsigned c) {
        const float* src = xwb + (size_t)c * 4096u;
        float* dst = &xwC[c & 1u][0];
        unsigned off = wv * 256u;                        // wave-uniform float offset
        gld16(src + off + lane * 4u, dst + off);
    };
    issue(0u);

    const float L2E = 1.4426950408889634f;
    const float DOT_SCALE = 6.2000124e-06f;   // 1/(127*1270)
    float hold = 0.f;

    auto step = [&](unsigned s, const unsigned char* hRd, unsigned char* hWr,
                    const float* xc, float* pfc) {
        uint4 h0 = *(const uint4*)(hRd + off_q0);
        uint4 h1 = *(const uint4*)(hRd + off_q1);
        int a0 = 0, a1 = 0, a2 = 0, a3 = 0;
        DOT4(a0, h0.x, w[0][0].x); DOT4(a1, h0.x, w[1][0].x);
        DOT4(a2, h0.x, w[2][0].x); DOT4(a3, h0.x, w[3][0].x);
        DOT4(a0, h0.y, w[0][0].y); DOT4(a1, h0.y, w[1][0].y);
        DOT4(a2, h0.y, w[2][0].y); DOT4(a3, h0.y, w[3][0].y);
        DOT4(a0, h0.z, w[0][0].z); DOT4(a1, h0.z, w[1][0].z);
        DOT4(a2, h0.z, w[2][0].z); DOT4(a3, h0.z, w[3][0].z);
        DOT4(a0, h0.w, w[0][0].w); DOT4(a1, h0.w, w[1][0].w);
        DOT4(a2, h0.w, w[2][0].w); DOT4(a3, h0.w, w[3][0].w);
        DOT4(a0, h1.x, w[0][1].x); DOT4(a1, h1.x, w[1][1].x);
        DOT4(a2, h1.x, w[2][1].x); DOT4(a3, h1.x, w[3][1].x);
        DOT4(a0, h1.y, w[0][1].y); DOT4(a1, h1.y, w[1][1].y);
        DOT4(a2, h1.y, w[2][1].y); DOT4(a3, h1.y, w[3][1].y);
        DOT4(a0, h1.z, w[0][1].z); DOT4(a1, h1.z, w[1][1].z);
        DOT4(a2, h1.z, w[2][1].z); DOT4(a3, h1.z, w[3][1].z);
        DOT4(a0, h1.w, w[0][1].w); DOT4(a1, h1.w, w[1][1].w);
        DOT4(a2, h1.w, w[2][1].w); DOT4(a3, h1.w, w[3][1].w);
        a0 = bsum8(a0); a1 = bsum8(a1); a2 = bsum8(a2); a3 = bsum8(a3);
        int ts = jc ? a1 : a0;
        int tg = jc ? a3 : a2;
        float sv = fmaf((float)ts, DOT_SCALE, xc[s * 512u + j]);
        float gv = fmaf((float)tg, DOT_SCALE, xc[s * 512u + 256u + j]);
        float gate = fast_rcp(1.f + fast_exp2(-gv * L2E));
        float prop = 1.f - 2.f * fast_rcp(1.f + fast_exp2(2.f * L2E * sv));
        float hnew = hold + gate * (prop - hold);
        if (ko < 2u) {
            pfc[s * 256u] = hold;                       // fire-and-forget
            int iv = (int)rintf(hnew * 127.f);
            hWr[j] = (unsigned char)((unsigned)iv & 0xFFu);
        }
        hold = hnew;
        if (s < 7u) STEP_BARRIER();
    };

    for (unsigned c = 0; c < 128u; ++c) {
        if (c == 0u) { asm volatile("s_waitcnt vmcnt(0) lgkmcnt(0)" ::: "memory"); }
        else         { asm volatile("s_waitcnt vmcnt(8) lgkmcnt(0)" ::: "memory"); }
        __builtin_amdgcn_s_barrier();
        asm volatile("" ::: "memory");
        if (c + 1u < 128u) issue(c + 1u);
        const float* xc = &xwC[c & 1u][0];
        float* pfc = pfb + c * 2048u;
#pragma unroll
        for (unsigned s = 0; s < 8u; ++s)
            step(s, (s & 1u) ? hbp1 : hbp0, (s & 1u) ? (unsigned char*)hbp0 : (unsigned char*)hbp1,
                 xc, pfc);
    }
}

// ---------------------------------------------------------------------------
// K5: router + delta mix at active tokens only. grid-stride over device count.
__launch_bounds__(256, 1)
__global__ void k_router(const unsigned* __restrict__ list, const float* __restrict__ accums_ro,
                         const float* __restrict__ prefix, const float* __restrict__ base,
                         const float* __restrict__ Wrh, const float* __restrict__ Wro,
                         const float* __restrict__ delta, float* __restrict__ out,
                         float* __restrict__ ent_sum) {
    const unsigned cnt = ((const unsigned*)accums_ro)[1];
    __shared__ float f[1280];
    __shared__ float hid[256];
    __shared__ float pr[16];
    const unsigned tid = threadIdx.x;
    for (unsigned idx = blockIdx.x; idx < cnt; idx += gridDim.x) {
        unsigned e = list[idx];
        unsigned tok = e >> 6, slot = e & 63u;
        f[tid] = prefix[(size_t)tok * 256u + tid];
#pragma unroll
        for (int q = 0; q < 4; q++)
            f[256u + q * 256u + tid] = base[(size_t)tok * 1024u + q * 256u + tid];
        __syncthreads();
        float a = 0.f;
        for (unsigned k = 0; k < 1280u; k++) a += f[k] * Wrh[k * 256u + tid];
        hid[tid] = tanhf(a);
        __syncthreads();
        if (tid < 16u) {
            float l = 0.f;
            for (unsigned k = 0; k < 256u; k++) l += hid[k] * Wro[k * 16u + tid];
            pr[tid] = l;
        }
        __syncthreads();
        if (tid == 0u) {
            float m = pr[0];
#pragma unroll
            for (int n = 1; n < 16; n++) m = fmaxf(m, pr[n]);
            float es[16]; float ssum = 0.f;
#pragma unroll
            for (int n = 0; n < 16; n++) { es[n] = expf(pr[n] - m); ssum += es[n]; }
            float inv = 1.f / ssum, ent = 0.f;
#pragma unroll
            for (int n = 0; n < 16; n++) {
                float p = es[n] * inv;
                pr[n] = p;
                ent -= p * logf(fmaxf(p, 1e-8f));
            }
            atomicAdd(ent_sum, ent);
        }
        __syncthreads();
        {
            const float* dslot = delta + (size_t)slot * 16u * 1024u;
            unsigned d0 = tid * 4u;
            float4 m4 = {0.f, 0.f, 0.f, 0.f};
#pragma unroll
            for (int n = 0; n < 16; n++) {
                float p = pr[n];
                float4 dv = *(const float4*)(dslot + n * 1024u + d0);
                m4.x += p * dv.x; m4.y += p * dv.y; m4.z += p * dv.z; m4.w += p * dv.w;
            }
            float* op = out + (size_t)tok * 1024u + d0;
            float4 cur = *(const float4*)op;
            cur.x += 0.25f * m4.x; cur.y += 0.25f * m4.y;
            cur.z += 0.25f * m4.z; cur.w += 0.25f * m4.w;
            *(float4*)op = cur;
        }
        __syncthreads();
    }
}

// ---------------------------------------------------------------------------
// K6: scalars
__global__ void k_final(const float* __restrict__ accums, float* __restrict__ out) {
    float ent = accums[0];
    unsigned cnt = ((const unsigned*)accums)[1];
    out[OUT_MAIN]     = (cnt > 0u) ? ent / (float)cnt : 0.f;
    out[OUT_MAIN + 1] = (float)cnt / 8192.f;
}

// ---------------------------------------------------------------------------
extern "C" void kernel_launch(void* const* d_in, const int* in_sizes, int n_in,
                              void* d_out, int out_size, void* d_ws, size_t ws_size,
                              hipStream_t stream) {
    const int*   ids  = (const int*)d_in[0];
    const float* base = (const float*)d_in[1];
    const int*   t2s  = (const int*)d_in[2];
    const float* Wsi  = (const float*)d_in[3];
    const float* Wsh  = (const float*)d_in[4];
    const float* Wgi  = (const float*)d_in[5];
    const float* Wgh  = (const float*)d_in[6];
    const float* Wrh  = (const float*)d_in[7];
    const float* Wro  = (const float*)d_in[8];
    const float* delta = (const float*)d_in[9];
    float* out = (float*)d_out;

    char* ws = (char*)d_ws;
    float*          XW     = (float*)(ws);                      // 16,777,216 B
    float*          prefix = (float*)(ws + 16777216);           //  8,388,608 B
    unsigned short* Bt     = (unsigned short*)(ws + 25165824);  //  1,048,576 B
    unsigned*       Wpack  = (unsigned*)(ws + 26214400);        //    131,072 B
    unsigned*       list   = (unsigned*)(ws + 26345472);        //     32,768 B
    float*          accums = (float*)(ws + 26378240);           //          8 B

    hipLaunchKernelGGL(k_copy_zero, dim3(2048), dim3(256), 0, stream,
                       (const float4*)base, (float4*)out, accums);
    hipLaunchKernelGGL(k_prep, dim3(2208), dim3(256), 0, stream,
                       Wsi, Wgi, Wsh, Wgh, ids, t2s, Bt, Wpack, list,
                       (unsigned*)accums + 1);
    hipLaunchKernelGGL(k_gemm, dim3(64, 2), dim3(512), 0, stream, base, Bt, XW);
    hipLaunchKernelGGL(k_rec, dim3(8), dim3(1024), 0, stream, XW, Wpack, prefix);
    hipLaunchKernelGGL(k_router, dim3(64), dim3(256), 0, stream,
                       list, accums, prefix, base, Wrh, Wro, delta, out, accums);
    hipLaunchKernelGGL(k_final, dim3(1), dim3(1), 0, stream, accums, out);
}

// Round 6
// 695.045 us; speedup vs baseline: 1.0919x; 1.0919x over previous
//
#include <hip/hip_runtime.h>
#include <hip/hip_bf16.h>
#include <hip/hip_fp16.h>

// Problem constants
#define NB 8
#define NT 1024
#define MD 1024
#define SD 256
#define NSTATES 16
#define NTOK (NB*NT)            // 8192
#define OUT_MAIN (NTOK*MD)      // 8388608

typedef __attribute__((ext_vector_type(8))) short bf16x8;
typedef __attribute__((ext_vector_type(4))) float f32x4;

static __device__ __forceinline__ unsigned short f32_to_bf16_bits(float f) {
    union { float f; unsigned u; } v; v.f = f;
    unsigned r = v.u + 0x7FFFu + ((v.u >> 16) & 1u);
    return (unsigned short)(r >> 16);
}

// i8 dot4 with MANDATORY VGPR operands (prevents AGPR homing of weights).
// CK-style idiom; v_dot4_i32_i8 is the VOP3P int8 dot on CDNA.
#define DOT4(acc, h, w) asm("v_dot4_i32_i8 %0, %1, %2, %0" : "+v"(acc) : "v"(h), "v"(w))

static __device__ __forceinline__ float fast_exp2(float x) {
#if __has_builtin(__builtin_amdgcn_exp2f)
    return __builtin_amdgcn_exp2f(x);
#else
    return exp2f(x);
#endif
}
static __device__ __forceinline__ float fast_rcp(float x) {
#if __has_builtin(__builtin_amdgcn_rcpf)
    return __builtin_amdgcn_rcpf(x);
#else
    return 1.f / x;
#endif
}

// int butterfly-add over 8 consecutive lanes: xor1, xor2, mirror-within-8
static __device__ __forceinline__ int bsum8(int v) {
    v += __builtin_amdgcn_update_dpp(0, v, 0xB1,  0xF, 0xF, true);  // quad_perm [1,0,3,2]
    v += __builtin_amdgcn_update_dpp(0, v, 0x4E,  0xF, 0xF, true);  // quad_perm [2,3,0,1]
    v += __builtin_amdgcn_update_dpp(0, v, 0x141, 0xF, 0xF, true);  // row_half_mirror
    return v;
}

#define STEP_BARRIER() do { \
    asm volatile("s_waitcnt lgkmcnt(0)" ::: "memory"); \
    __builtin_amdgcn_s_barrier(); \
    asm volatile("" ::: "memory"); } while (0)

// ---------------------------------------------------------------------------
// K1: out = base (exact f32 copy), zero accumulators (ent_sum f32, count u32)
__global__ void k_copy_zero(const float4* __restrict__ base, float4* __restrict__ out,
                            float* __restrict__ accums) {
    unsigned i = blockIdx.x * 256u + threadIdx.x;
    const unsigned STRIDE = 524288u; // total float4 = 2097152
#pragma unroll
    for (int q = 0; q < 4; q++) out[i + q * STRIDE] = base[i + q * STRIDE];
    if (i == 0u) { accums[0] = 0.f; ((unsigned*)accums)[1] = 0u; }
}

// ---------------------------------------------------------------------------
// K2: prep weights + active list (identical layout to round-4).
//  - Bt[512][1024] bf16 : row n = column n of [Wsi|Wgi]
//  - Wpack: int8 recurrent weights (scale 1270), per-thread packed for the
//    512-thread k_rec: w in [0,32768): e=w&3, tid=(w>>2)&511, i4=w>>11 (0..15):
//    q=i4&1, a=i4>>1 (0..7); lane=tid&63, wv=tid>>6, ko=lane&7, jg=lane>>3,
//    G=wv*8+jg, j=4G+(a&3), o=a>>2 (0:Wsh,1:Wgh), c=(q^(ko&1))&1,
//    k0=ko*32+c*16+e*4; uint packs W_o[k0+r][j], r=0..3 (LE bytes)
//  - active list: (tok<<6)|slot appended with atomic counter
__global__ void k_prep(const float* __restrict__ Wsi, const float* __restrict__ Wgi,
                       const float* __restrict__ Wsh, const float* __restrict__ Wgh,
                       const int* __restrict__ ids, const int* __restrict__ t2s,
                       unsigned short* __restrict__ Bt, unsigned* __restrict__ Wpack,
                       unsigned* __restrict__ list, unsigned* __restrict__ countp) {
    unsigned i = blockIdx.x * 256u + threadIdx.x;
    if (i < 524288u) {
        unsigned n = i >> 10, k = i & 1023u;
        float v = (n < 256u) ? Wsi[k * 256u + n] : Wgi[k * 256u + (n - 256u)];
        Bt[i] = f32_to_bf16_bits(v);
    } else if (i < 557056u) {
        unsigned w = i - 524288u;            // 0..32767
        unsigned e   = w & 3u;
        unsigned tid = (w >> 2) & 511u;
        unsigned i4  = w >> 11;              // 0..15
        unsigned q   = i4 & 1u;
        unsigned a   = i4 >> 1;              // 0..7
        unsigned lane = tid & 63u, wv = tid >> 6;
        unsigned ko = lane & 7u, jg = lane >> 3;
        unsigned G  = wv * 8u + jg;
        unsigned j  = 4u * G + (a & 3u);
        unsigned c  = (q ^ (ko & 1u)) & 1u;
        unsigned k0 = ko * 32u + c * 16u + e * 4u;
        const float* W = (a >> 2) ? Wgh : Wsh;
        unsigned word = 0u;
#pragma unroll
        for (int r = 0; r < 4; r++) {
            float wf = W[(k0 + (unsigned)r) * 256u + j];
            int iv = (int)rintf(wf * 1270.f);
            iv = iv > 127 ? 127 : (iv < -127 ? -127 : iv);
            word |= ((unsigned)iv & 0xFFu) << (8 * r);
        }
        Wpack[w] = word;
    } else if (i < 565248u) {
        unsigned tok = i - 557056u;
        int slot = t2s[ids[tok]];
        if (slot >= 0) {
            unsigned pos = atomicAdd(countp, 1u);
            list[pos] = (tok << 6) | (unsigned)slot;
        }
    }
}

// ---------------------------------------------------------------------------
// K3: XW[8192][512] f32 = bf16(base) @ [Wsi|Wgi]  (unchanged)
__launch_bounds__(512, 1)
__global__ void k_gemm(const float* __restrict__ A, const unsigned short* __restrict__ Bt,
                       float* __restrict__ XW) {
    __shared__ __align__(16) unsigned short Abuf[128 * 40];
    __shared__ __align__(16) unsigned short Bbuf[256 * 40];
    const unsigned tid = threadIdx.x;
    const unsigned m0 = blockIdx.x * 128u;
    const unsigned n0 = blockIdx.y * 256u;
    const unsigned wave = tid >> 6, lane = tid & 63u;
    const unsigned wm = wave >> 2, wn = wave & 3u;
    const unsigned l15 = lane & 15u, kg = lane >> 4;
    const unsigned ar = tid >> 2;
    const unsigned ac = (tid & 3u) * 8u;

    f32x4 acc[4][4];
#pragma unroll
    for (int i = 0; i < 4; i++)
#pragma unroll
        for (int j = 0; j < 4; j++) acc[i][j] = (f32x4){0.f, 0.f, 0.f, 0.f};

    for (unsigned k0 = 0; k0 < 1024u; k0 += 32u) {
        {
            const float* src = A + (size_t)(m0 + ar) * 1024u + k0 + ac;
            float4 f0 = *(const float4*)src;
            float4 f1 = *(const float4*)(src + 4);
            unsigned short* dst = &Abuf[ar * 40u + ac];
            dst[0] = f32_to_bf16_bits(f0.x); dst[1] = f32_to_bf16_bits(f0.y);
            dst[2] = f32_to_bf16_bits(f0.z); dst[3] = f32_to_bf16_bits(f0.w);
            dst[4] = f32_to_bf16_bits(f1.x); dst[5] = f32_to_bf16_bits(f1.y);
            dst[6] = f32_to_bf16_bits(f1.z); dst[7] = f32_to_bf16_bits(f1.w);
        }
#pragma unroll
        for (int q = 0; q < 2; q++) {
            unsigned br = q * 128u + (tid >> 2);
            const unsigned short* src = Bt + (size_t)(n0 + br) * 1024u + k0 + ac;
            *(uint4*)&Bbuf[br * 40u + ac] = *(const uint4*)src;
        }
        __syncthreads();
        bf16x8 a[4], b[4];
#pragma unroll
        for (int i = 0; i < 4; i++)
            a[i] = *(const bf16x8*)&Abuf[(wm * 64u + i * 16u + l15) * 40u + kg * 8u];
#pragma unroll
        for (int j = 0; j < 4; j++)
            b[j] = *(const bf16x8*)&Bbuf[(wn * 64u + j * 16u + l15) * 40u + kg * 8u];
#pragma unroll
        for (int i = 0; i < 4; i++)
#pragma unroll
            for (int j = 0; j < 4; j++)
                acc[i][j] = __builtin_amdgcn_mfma_f32_16x16x32_bf16(a[i], b[j], acc[i][j], 0, 0, 0);
        __syncthreads();
    }
#pragma unroll
    for (int i = 0; i < 4; i++) {
        unsigned row_b = m0 + wm * 64u + i * 16u + kg * 4u;
#pragma unroll
        for (int j = 0; j < 4; j++) {
            unsigned col = n0 + wn * 64u + j * 16u + l15;
#pragma unroll
            for (int r = 0; r < 4; r++)
                XW[(size_t)(row_b + r) * 512u + col] = acc[i][j][r];
        }
    }
}

// ---------------------------------------------------------------------------
// K4: sequential GRU recurrence, v6 (int8 asm-dot4, 512 threads, no LDS xw).
// Same mapping as r4: lane octet ko splits K into 32-i8 slices; octet owns
// columns 4G..4G+3 for s and g. Weights pinned to VGPRs via asm "v"
// constraints on every dot. xw read directly global->regs, double-buffered
// one 8-step chunk ahead (latency hidden under compute). LDS holds only the
// 2x256B h double buffer; one lgkmcnt barrier per step; prefix stores
// fire-and-forget (never drained).
__launch_bounds__(512, 2)
__global__ void k_rec(const float* __restrict__ XW, const unsigned* __restrict__ Wpack,
                      float* __restrict__ prefix) {
    __shared__ __align__(16) unsigned char hB[2][256];
    const unsigned tid = threadIdx.x;
    const unsigned lane = tid & 63u, wv = tid >> 6;
    const unsigned ko = lane & 7u, jg = lane >> 3;
    const unsigned G = wv * 8u + jg;
    const unsigned jc = ko & 3u;
    const unsigned j = 4u * G + jc;
    const unsigned b = blockIdx.x;

    // register-resident weights: 16 uint4 = 64 VGPRs of packed i8
    uint4 w[8][2];
#pragma unroll
    for (int a = 0; a < 8; a++)
#pragma unroll
        for (int q = 0; q < 2; q++)
            w[a][q] = ((const uint4*)Wpack)[(a * 2 + q) * 512 + tid];

    if (tid < 128u) ((unsigned*)&hB[0][0])[tid] = 0u;   // zero both h buffers
    __syncthreads();

    // per-lane h read offsets (XOR order across the octet, matches Wpack)
    const unsigned c0 = ko & 1u;
    const unsigned off_q0 = ko * 32u + c0 * 16u;
    const unsigned off_q1 = ko * 32u + (c0 ^ 1u) * 16u;

    const float* xwb = XW + (size_t)b * (1024u * 512u);
    float* pfb = prefix + (size_t)b * (1024u * 256u) + j;

    const float L2E = 1.4426950408889634f;
    const float DOT_SCALE = 6.2000124e-06f;   // 1/(127*1270)
    float hold = 0.f;

    float bufA[16], bufB[16];
#define LOADBUF(buf, c) do { \
    const float* _s = xwb + (size_t)(c) * 4096u + j; \
    _Pragma("unroll") \
    for (int _q = 0; _q < 8; _q++) { \
        (buf)[_q * 2 + 0] = _s[_q * 512]; \
        (buf)[_q * 2 + 1] = _s[_q * 512 + 256]; \
    } } while (0)

#define STEP(s, bufU, c) do { \
    const unsigned char* _hRd = &hB[(s) & 1][0]; \
    unsigned char* _hWr = &hB[((s) + 1) & 1][0]; \
    uint4 h0 = *(const uint4*)(_hRd + off_q0); \
    uint4 h1 = *(const uint4*)(_hRd + off_q1); \
    int a0 = 0, a1 = 0, a2 = 0, a3 = 0, a4 = 0, a5 = 0, a6 = 0, a7 = 0; \
    DOT4(a0, h0.x, w[0][0].x); DOT4(a1, h0.x, w[1][0].x); \
    DOT4(a2, h0.x, w[2][0].x); DOT4(a3, h0.x, w[3][0].x); \
    DOT4(a4, h0.x, w[4][0].x); DOT4(a5, h0.x, w[5][0].x); \
    DOT4(a6, h0.x, w[6][0].x); DOT4(a7, h0.x, w[7][0].x); \
    DOT4(a0, h0.y, w[0][0].y); DOT4(a1, h0.y, w[1][0].y); \
    DOT4(a2, h0.y, w[2][0].y); DOT4(a3, h0.y, w[3][0].y); \
    DOT4(a4, h0.y, w[4][0].y); DOT4(a5, h0.y, w[5][0].y); \
    DOT4(a6, h0.y, w[6][0].y); DOT4(a7, h0.y, w[7][0].y); \
    DOT4(a0, h0.z, w[0][0].z); DOT4(a1, h0.z, w[1][0].z); \
    DOT4(a2, h0.z, w[2][0].z); DOT4(a3, h0.z, w[3][0].z); \
    DOT4(a4, h0.z, w[4][0].z); DOT4(a5, h0.z, w[5][0].z); \
    DOT4(a6, h0.z, w[6][0].z); DOT4(a7, h0.z, w[7][0].z); \
    DOT4(a0, h0.w, w[0][0].w); DOT4(a1, h0.w, w[1][0].w); \
    DOT4(a2, h0.w, w[2][0].w); DOT4(a3, h0.w, w[3][0].w); \
    DOT4(a4, h0.w, w[4][0].w); DOT4(a5, h0.w, w[5][0].w); \
    DOT4(a6, h0.w, w[6][0].w); DOT4(a7, h0.w, w[7][0].w); \
    DOT4(a0, h1.x, w[0][1].x); DOT4(a1, h1.x, w[1][1].x); \
    DOT4(a2, h1.x, w[2][1].x); DOT4(a3, h1.x, w[3][1].x); \
    DOT4(a4, h1.x, w[4][1].x); DOT4(a5, h1.x, w[5][1].x); \
    DOT4(a6, h1.x, w[6][1].x); DOT4(a7, h1.x, w[7][1].x); \
    DOT4(a0, h1.y, w[0][1].y); DOT4(a1, h1.y, w[1][1].y); \
    DOT4(a2, h1.y, w[2][1].y); DOT4(a3, h1.y, w[3][1].y); \
    DOT4(a4, h1.y, w[4][1].y); DOT4(a5, h1.y, w[5][1].y); \
    DOT4(a6, h1.y, w[6][1].y); DOT4(a7, h1.y, w[7][1].y); \
    DOT4(a0, h1.z, w[0][1].z); DOT4(a1, h1.z, w[1][1].z); \
    DOT4(a2, h1.z, w[2][1].z); DOT4(a3, h1.z, w[3][1].z); \
    DOT4(a4, h1.z, w[4][1].z); DOT4(a5, h1.z, w[5][1].z); \
    DOT4(a6, h1.z, w[6][1].z); DOT4(a7, h1.z, w[7][1].z); \
    DOT4(a0, h1.w, w[0][1].w); DOT4(a1, h1.w, w[1][1].w); \
    DOT4(a2, h1.w, w[2][1].w); DOT4(a3, h1.w, w[3][1].w); \
    DOT4(a4, h1.w, w[4][1].w); DOT4(a5, h1.w, w[5][1].w); \
    DOT4(a6, h1.w, w[6][1].w); DOT4(a7, h1.w, w[7][1].w); \
    a0 = bsum8(a0); a1 = bsum8(a1); a2 = bsum8(a2); a3 = bsum8(a3); \
    a4 = bsum8(a4); a5 = bsum8(a5); a6 = bsum8(a6); a7 = bsum8(a7); \
    int ts = (jc & 2u) ? ((jc & 1u) ? a3 : a2) : ((jc & 1u) ? a1 : a0); \
    int tg = (jc & 2u) ? ((jc & 1u) ? a7 : a6) : ((jc & 1u) ? a5 : a4); \
    float sv = fmaf((float)ts, DOT_SCALE, (bufU)[(s) * 2 + 0]); \
    float gv = fmaf((float)tg, DOT_SCALE, (bufU)[(s) * 2 + 1]); \
    float gate = fast_rcp(1.f + fast_exp2(-gv * L2E)); \
    float prop = 1.f - 2.f * fast_rcp(1.f + fast_exp2(2.f * L2E * sv)); \
    float hnew = hold + gate * (prop - hold); \
    if (ko < 4u) { \
        pfb[(size_t)((c) * 8u + (s)) * 256u] = hold; \
        _hWr[j] = (unsigned char)((unsigned)(int)rintf(hnew * 127.f) & 0xFFu); \
    } \
    hold = hnew; \
    STEP_BARRIER(); } while (0)

    LOADBUF(bufA, 0u);
    for (unsigned c = 0; c < 128u; c += 2u) {
        LOADBUF(bufB, c + 1u);                       // prefetch next chunk
        STEP(0, bufA, c); STEP(1, bufA, c); STEP(2, bufA, c); STEP(3, bufA, c);
        STEP(4, bufA, c); STEP(5, bufA, c); STEP(6, bufA, c); STEP(7, bufA, c);
        if (c + 2u < 128u) LOADBUF(bufA, c + 2u);    // prefetch next-next
        STEP(0, bufB, c + 1u); STEP(1, bufB, c + 1u); STEP(2, bufB, c + 1u); STEP(3, bufB, c + 1u);
        STEP(4, bufB, c + 1u); STEP(5, bufB, c + 1u); STEP(6, bufB, c + 1u); STEP(7, bufB, c + 1u);
    }
#undef STEP
#undef LOADBUF
}

// ---------------------------------------------------------------------------
// K5: router + delta mix at active tokens only. grid-stride over device count.
__launch_bounds__(256, 1)
__global__ void k_router(const unsigned* __restrict__ list, const float* __restrict__ accums_ro,
                         const float* __restrict__ prefix, const float* __restrict__ base,
                         const float* __restrict__ Wrh, const float* __restrict__ Wro,
                         const float* __restrict__ delta, float* __restrict__ out,
                         float* __restrict__ ent_sum) {
    const unsigned cnt = ((const unsigned*)accums_ro)[1];
    __shared__ float f[1280];
    __shared__ float hid[256];
    __shared__ float pr[16];
    const unsigned tid = threadIdx.x;
    for (unsigned idx = blockIdx.x; idx < cnt; idx += gridDim.x) {
        unsigned e = list[idx];
        unsigned tok = e >> 6, slot = e & 63u;
        f[tid] = prefix[(size_t)tok * 256u + tid];
#pragma unroll
        for (int q = 0; q < 4; q++)
            f[256u + q * 256u + tid] = base[(size_t)tok * 1024u + q * 256u + tid];
        __syncthreads();
        float a = 0.f;
        for (unsigned k = 0; k < 1280u; k++) a += f[k] * Wrh[k * 256u + tid];
        hid[tid] = tanhf(a);
        __syncthreads();
        if (tid < 16u) {
            float l = 0.f;
            for (unsigned k = 0; k < 256u; k++) l += hid[k] * Wro[k * 16u + tid];
            pr[tid] = l;
        }
        __syncthreads();
        if (tid == 0u) {
            float m = pr[0];
#pragma unroll
            for (int n = 1; n < 16; n++) m = fmaxf(m, pr[n]);
            float es[16]; float ssum = 0.f;
#pragma unroll
            for (int n = 0; n < 16; n++) { es[n] = expf(pr[n] - m); ssum += es[n]; }
            float inv = 1.f / ssum, ent = 0.f;
#pragma unroll
            for (int n = 0; n < 16; n++) {
                float p = es[n] * inv;
                pr[n] = p;
                ent -= p * logf(fmaxf(p, 1e-8f));
            }
            atomicAdd(ent_sum, ent);
        }
        __syncthreads();
        {
            const float* dslot = delta + (size_t)slot * 16u * 1024u;
            unsigned d0 = tid * 4u;
            float4 m4 = {0.f, 0.f, 0.f, 0.f};
#pragma unroll
            for (int n = 0; n < 16; n++) {
                float p = pr[n];
                float4 dv = *(const float4*)(dslot + n * 1024u + d0);
                m4.x += p * dv.x; m4.y += p * dv.y; m4.z += p * dv.z; m4.w += p * dv.w;
            }
            float* op = out + (size_t)tok * 1024u + d0;
            float4 cur = *(const float4*)op;
            cur.x += 0.25f * m4.x; cur.y += 0.25f * m4.y;
            cur.z += 0.25f * m4.z; cur.w += 0.25f * m4.w;
            *(float4*)op = cur;
        }
        __syncthreads();
    }
}

// ---------------------------------------------------------------------------
// K6: scalars
__global__ void k_final(const float* __restrict__ accums, float* __restrict__ out) {
    float ent = accums[0];
    unsigned cnt = ((const unsigned*)accums)[1];
    out[OUT_MAIN]     = (cnt > 0u) ? ent / (float)cnt : 0.f;
    out[OUT_MAIN + 1] = (float)cnt / 8192.f;
}

// ---------------------------------------------------------------------------
extern "C" void kernel_launch(void* const* d_in, const int* in_sizes, int n_in,
                              void* d_out, int out_size, void* d_ws, size_t ws_size,
                              hipStream_t stream) {
    const int*   ids  = (const int*)d_in[0];
    const float* base = (const float*)d_in[1];
    const int*   t2s  = (const int*)d_in[2];
    const float* Wsi  = (const float*)d_in[3];
    const float* Wsh  = (const float*)d_in[4];
    const float* Wgi  = (const float*)d_in[5];
    const float* Wgh  = (const float*)d_in[6];
    const float* Wrh  = (const float*)d_in[7];
    const float* Wro  = (const float*)d_in[8];
    const float* delta = (const float*)d_in[9];
    float* out = (float*)d_out;

    char* ws = (char*)d_ws;
    float*          XW     = (float*)(ws);                      // 16,777,216 B
    float*          prefix = (float*)(ws + 16777216);           //  8,388,608 B
    unsigned short* Bt     = (unsigned short*)(ws + 25165824);  //  1,048,576 B
    unsigned*       Wpack  = (unsigned*)(ws + 26214400);        //    131,072 B
    unsigned*       list   = (unsigned*)(ws + 26345472);        //     32,768 B
    float*          accums = (float*)(ws + 26378240);           //          8 B

    hipLaunchKernelGGL(k_copy_zero, dim3(2048), dim3(256), 0, stream,
                       (const float4*)base, (float4*)out, accums);
    hipLaunchKernelGGL(k_prep, dim3(2208), dim3(256), 0, stream,
                       Wsi, Wgi, Wsh, Wgh, ids, t2s, Bt, Wpack, list,
                       (unsigned*)accums + 1);
    hipLaunchKernelGGL(k_gemm, dim3(64, 2), dim3(512), 0, stream, base, Bt, XW);
    hipLaunchKernelGGL(k_rec, dim3(8), dim3(512), 0, stream, XW, Wpack, prefix);
    hipLaunchKernelGGL(k_router, dim3(64), dim3(256), 0, stream,
                       list, accums, prefix, base, Wrh, Wro, delta, out, accums);
    hipLaunchKernelGGL(k_final, dim3(1), dim3(1), 0, stream, accums, out);
}